// Round 2
// baseline (225.958 us; speedup 1.0000x reference)
//
#include <hip/hip_runtime.h>
#include <math.h>

// Cost weights / focal params (match reference)
#define W_CLASS 1.0f
#define W_BBOX  5.0f
#define W_GIOU  2.0f
#define F_ALPHA 0.25f
#define F_EPS   1e-8f

// Phase 1: per-row softmax over C=128 logits + focal class-cost table.
// delta[n*128 + c] = pos_cost(n,c) - neg_cost(n,c)
// One wave (64 lanes) per row, 4 rows per 256-thread block.
__global__ void class_cost_kernel(const float* __restrict__ logits,
                                  float* __restrict__ delta) {
    const int wave = threadIdx.x >> 6;
    const int lane = threadIdx.x & 63;
    const int n = blockIdx.x * 4 + wave;
    const float* row = logits + (size_t)n * 128;

    float x0 = row[lane];
    float x1 = row[lane + 64];

    float m = fmaxf(x0, x1);
    #pragma unroll
    for (int off = 32; off > 0; off >>= 1)
        m = fmaxf(m, __shfl_xor(m, off));

    float e0 = __expf(x0 - m);
    float e1 = __expf(x1 - m);
    float s = e0 + e1;
    #pragma unroll
    for (int off = 32; off > 0; off >>= 1)
        s += __shfl_xor(s, off);
    float inv = 1.0f / s;

    float p0 = e0 * inv;
    float p1 = e1 * inv;

    float omp0 = 1.0f - p0;
    float d0 = F_ALPHA * omp0 * omp0 * (-__logf(p0 + F_EPS))
             - (1.0f - F_ALPHA) * p0 * p0 * (-__logf(1.0f - p0 + F_EPS));
    float omp1 = 1.0f - p1;
    float d1 = F_ALPHA * omp1 * omp1 * (-__logf(p1 + F_EPS))
             - (1.0f - F_ALPHA) * p1 * p1 * (-__logf(1.0f - p1 + F_EPS));

    delta[(size_t)n * 128 + lane]      = d0;
    delta[(size_t)n * 128 + lane + 64] = d1;
}

// Phase 2: full cost matrix.
// Each thread handles 4 consecutive targets (float4 store = 16 B/lane).
// Block = 4 waves; each wave covers RPW rows; block covers 4*RPW rows.
// t-tile per block = 64 lanes * 4 = 256 targets.
#define RPW 4

__global__ __launch_bounds__(256)
void cost_kernel(const float4* __restrict__ pred_boxes,   // [N,4] cxcywh
                 const float4* __restrict__ tgt_bbox,     // [T,4] cxcywh
                 const int4*  __restrict__ tgt_ids4,      // [T/4]
                 const float* __restrict__ delta,         // [N,128]
                 float* __restrict__ out,                 // [N,T]
                 int T, int N) {
    const int lane = threadIdx.x & 63;
    const int wave = threadIdx.x >> 6;
    const int t0 = blockIdx.x * 256 + lane * 4;
    const bool active = (t0 < T);        // T % 4 == 0: all-4-valid or none
    const int tt = active ? t0 : 0;

    // Load 4 targets: boxes (64 B contiguous) + ids (16 B)
    float4 tb[4];
    tb[0] = tgt_bbox[tt + 0];
    tb[1] = tgt_bbox[tt + 1];
    tb[2] = tgt_bbox[tt + 2];
    tb[3] = tgt_bbox[tt + 3];
    const int4 ids = tgt_ids4[tt >> 2];
    const int id[4] = {ids.x, ids.y, ids.z, ids.w};

    // Precompute tgt xyxy + area
    float tx0[4], ty0[4], tx1[4], ty1[4], ta[4];
    #pragma unroll
    for (int j = 0; j < 4; ++j) {
        tx0[j] = tb[j].x - 0.5f * tb[j].z;
        ty0[j] = tb[j].y - 0.5f * tb[j].w;
        tx1[j] = tb[j].x + 0.5f * tb[j].z;
        ty1[j] = tb[j].y + 0.5f * tb[j].w;
        ta[j]  = (tx1[j] - tx0[j]) * (ty1[j] - ty0[j]);
    }

    const int nbase = blockIdx.y * (4 * RPW) + wave * RPW;

    #pragma unroll
    for (int r = 0; r < RPW; ++r) {
        const int n = nbase + r;
        if (n >= N) break;               // uniform branch
        const float4 pb = pred_boxes[n]; // wave-uniform -> scalar load
        const float px0 = pb.x - 0.5f * pb.z, py0 = pb.y - 0.5f * pb.w;
        const float px1 = pb.x + 0.5f * pb.z, py1 = pb.y + 0.5f * pb.w;
        const float pa  = (px1 - px0) * (py1 - py0);
        const float* __restrict__ drow = delta + n * 128;

        float rr[4];
        #pragma unroll
        for (int j = 0; j < 4; ++j) {
            const float d = drow[id[j]];     // 4B gather within 512B row (L1)

            float cb = fabsf(pb.x - tb[j].x) + fabsf(pb.y - tb[j].y)
                     + fabsf(pb.z - tb[j].z) + fabsf(pb.w - tb[j].w);

            float ix0 = fmaxf(px0, tx0[j]), iy0 = fmaxf(py0, ty0[j]);
            float ix1 = fminf(px1, tx1[j]), iy1 = fminf(py1, ty1[j]);
            float iw = fmaxf(ix1 - ix0, 0.0f), ih = fmaxf(iy1 - iy0, 0.0f);
            float inter = iw * ih;
            float uni = pa + ta[j] - inter;

            float ex0 = fminf(px0, tx0[j]), ey0 = fminf(py0, ty0[j]);
            float ex1 = fmaxf(px1, tx1[j]), ey1 = fmaxf(py1, ty1[j]);
            float ea = (ex1 - ex0) * (ey1 - ey0);

            // fast reciprocal (v_rcp_f32, ~1 ulp): plenty of accuracy slack
            float giou = inter * __builtin_amdgcn_rcpf(uni)
                       - (ea - uni) * __builtin_amdgcn_rcpf(ea);

            rr[j] = W_BBOX * cb + W_CLASS * d - W_GIOU * giou;
        }

        if (active) {
            *(float4*)(out + (size_t)n * T + t0) =
                make_float4(rr[0], rr[1], rr[2], rr[3]);
        }
    }
}

extern "C" void kernel_launch(void* const* d_in, const int* in_sizes, int n_in,
                              void* d_out, int out_size, void* d_ws, size_t ws_size,
                              hipStream_t stream) {
    const float* pred_logits = (const float*)d_in[0];   // [16,900,128] f32
    const float* pred_boxes  = (const float*)d_in[1];   // [16,900,4]  f32
    const int*   tgt_ids     = (const int*)d_in[2];     // [3200] int32
    const float* tgt_bbox    = (const float*)d_in[3];   // [3200,4] f32
    float* out = (float*)d_out;
    float* delta = (float*)d_ws;                        // [14400,128] f32 = 7.4 MB

    const int N = in_sizes[1] / 4;   // bs*Q = 14400
    const int T = in_sizes[2];       // 3200

    class_cost_kernel<<<N / 4, 256, 0, stream>>>(pred_logits, delta);

    dim3 grid((T + 255) / 256, (N + 4 * RPW - 1) / (4 * RPW));
    cost_kernel<<<grid, 256, 0, stream>>>(
        (const float4*)pred_boxes, (const float4*)tgt_bbox,
        (const int4*)tgt_ids, delta, out, T, N);
}